// Round 5
// baseline (1223.848 us; speedup 1.0000x reference)
//
#include <hip/hip_runtime.h>
#include <hip/hip_bf16.h>
#include <math.h>

#define N_NODE 30000
#define N_TRI  200000
#define DIM    128
#define OUTD   768
#define BATCH  2048
#define NROWA  4096
#define EPAD   30080   // 235*128
#define PADN   80      // EPAD - N_NODE
#define NTILE_E 235
#define NTILE_A 32
#define TILE_ELEMS (128*OUTD)
#define KBLK_ELEMS (128*32)
#define GAMMA_C 3.0f
#define LAMB_C  30.0f
#define TAU_C   10.0f

typedef __attribute__((ext_vector_type(8))) __bf16 bf16x8;
typedef __attribute__((ext_vector_type(8))) _Float16 half8;
typedef __attribute__((ext_vector_type(4))) float f32x4;

__device__ __forceinline__ float waveSum(float v){
#pragma unroll
  for (int m=1;m<64;m<<=1) v += __shfl_xor(v, m, 64);
  return v;
}
__device__ __forceinline__ float waveMax(float v){
#pragma unroll
  for (int m=1;m<64;m<<=1) v = fmaxf(v, __shfl_xor(v, m, 64));
  return v;
}

__device__ __forceinline__ void atomicMinF(float* a, float v){
  if (v >= 0.f) atomicMin((int*)a, __float_as_int(v));
  else          atomicMax((unsigned int*)a, __float_as_uint(v));
}

__device__ __forceinline__ void gl2lds16(const void* g, void* l){
  __builtin_amdgcn_global_load_lds(
      (const __attribute__((address_space(1))) char*)g,
      (__attribute__((address_space(3))) char*)l, 16, 0, 0);
}

__device__ __forceinline__ int swz_off(int r, int q){
  return r*32 + ((q ^ ((r>>1)&3))<<3);
}

__device__ __forceinline__ size_t negBase(int bi, int bj, int wave, int lane){
  return ((((size_t)bi*NTILE_E + bj)*4 + wave)*64 + lane)*64;
}

// ---------------- fill ----------------
__global__ void k_fill(float* __restrict__ p, long n, float v){
  long i = (long)blockIdx.x*blockDim.x + threadIdx.x;
  long st = (long)gridDim.x*blockDim.x;
  for (; i<n; i+=st) p[i]=v;
}

// ---------------- CSR build ----------------
__global__ __launch_bounds__(256) void k_hist(const int* __restrict__ rows, int* __restrict__ cnt){
  int t = blockIdx.x*256 + threadIdx.x;
  if (t < N_TRI) atomicAdd(&cnt[rows[t]], 1);
}

__global__ __launch_bounds__(256) void k_scan3(
    const int* __restrict__ c0, int* __restrict__ r0,
    const int* __restrict__ c1, int* __restrict__ r1,
    const int* __restrict__ c2, int* __restrict__ r2, int n){
  const int* cnt = blockIdx.x==0 ? c0 : (blockIdx.x==1 ? c1 : c2);
  int* rp        = blockIdx.x==0 ? r0 : (blockIdx.x==1 ? r1 : r2);
  __shared__ int buf[256];
  __shared__ int carry;
  if (threadIdx.x==0) carry = 0;
  __syncthreads();
  for (int base=0; base<n; base+=256){
    int i = base + threadIdx.x;
    int v = (i<n) ? cnt[i] : 0;
    buf[threadIdx.x] = v;
    __syncthreads();
    for (int off=1; off<256; off<<=1){
      int t = (threadIdx.x>=off) ? buf[threadIdx.x-off] : 0;
      __syncthreads();
      buf[threadIdx.x] += t;
      __syncthreads();
    }
    if (i<n) rp[i] = carry + buf[threadIdx.x] - v;
    int tot = buf[255];
    __syncthreads();
    if (threadIdx.x==0) carry += tot;
    __syncthreads();
  }
  if (threadIdx.x==0) rp[n] = carry;
}

__global__ __launch_bounds__(256) void k_place(const int* __restrict__ rows, const int* __restrict__ vals,
                        const int* __restrict__ rowptr, int* __restrict__ cur, int* __restrict__ idx, int mode){
  int t = blockIdx.x*256 + threadIdx.x;
  if (t < N_TRI){
    int r = rows[t];
    int p = atomicAdd(&cur[r], 1);
    idx[rowptr[r] + p] = mode ? vals[t] : t;
  }
}

// ---------------- fused sparse means + tanh ----------------
__global__ __launch_bounds__(256) void k_feat0(
    const int* __restrict__ rpE, const int* __restrict__ idxE,
    const int* __restrict__ rpR, const int* __restrict__ idxR,
    const float* __restrict__ ent_emb, const float* __restrict__ rel_emb,
    float* __restrict__ out){
  int wave = threadIdx.x>>6, lane = threadIdx.x&63;
  int i = blockIdx.x*4 + wave;
  if (i >= N_NODE) return;
  int bE = rpE[i], eE = rpE[i+1];
  int bR = rpR[i], eR = rpR[i+1];
  float2 aE = {0.f,0.f}, aR = {0.f,0.f};
  for (int k=bE; k<eE; ++k){
    int c = idxE[k];
    float2 v = *(const float2*)(ent_emb + (size_t)c*DIM + lane*2);
    aE.x += v.x; aE.y += v.y;
  }
  for (int k=bR; k<eR; ++k){
    int c = idxR[k];
    float2 v = *(const float2*)(rel_emb + (size_t)c*DIM + lane*2);
    aR.x += v.x; aR.y += v.y;
  }
  float ie = 1.f/fmaxf((float)(eE-bE), 1.f);
  float ir = 1.f/fmaxf((float)(eR-bR), 1.f);
  float2 oE = { tanhf(aE.x*ie), tanhf(aE.y*ie) };
  float2 oR = { tanhf(aR.x*ir), tanhf(aR.y*ir) };
  *(float2*)(out + (size_t)i*OUTD +   0 + lane*2) = oE;
  *(float2*)(out + (size_t)i*OUTD + 384 + lane*2) = oR;
}

// ---------------- tri_rel direct + norm + att logits ----------------
__global__ __launch_bounds__(256) void k_trinorm(
    const int* __restrict__ ridx1, const float* __restrict__ rval,
    const float* __restrict__ rel_emb,
    float* __restrict__ tri, const float* __restrict__ attnE,
    const float* __restrict__ attnR, float* __restrict__ att4){
  __shared__ float ak[4][DIM];
  int tid = threadIdx.x;
  for (int idx=tid; idx<4*DIM; idx+=256){
    int k = idx>>7, d = idx&127;
    ak[k][d] = (k<2) ? attnE[k*DIM + d] : attnR[(k-2)*DIM + d];
  }
  __syncthreads();
  int wave = tid>>6, lane = tid&63;
  int t = blockIdx.x*4 + wave;
  if (t >= N_TRI) return;
  int rr = ridx1[t];
  float rv = rval[t];
  float2 v = *(const float2*)(rel_emb + (size_t)rr*DIM + lane*2);
  v.x *= rv; v.y *= rv;
  float ss = waveSum(v.x*v.x + v.y*v.y);
  float inv = 1.f/fmaxf(sqrtf(ss), 1e-12f);
  v.x *= inv; v.y *= inv;
  *(float2*)(tri + (size_t)t*DIM + lane*2) = v;
#pragma unroll
  for (int k=0;k<4;k++){
    float p = waveSum(v.x*ak[k][lane*2] + v.y*ak[k][lane*2+1]);
    if (lane==0) att4[(size_t)k*N_TRI + t] = p;
  }
}

// ---------------- fused GAT layer (both branches) ----------------
__global__ __launch_bounds__(256) void k_gat(
    const int* __restrict__ rowptr, const int* __restrict__ idx, const int* __restrict__ cols,
    const float* __restrict__ tri,
    const float* __restrict__ attA, const float* __restrict__ attB,
    float* __restrict__ out, int inA, int outA, int inB, int outB){
  int wave = threadIdx.x>>6, lane = threadIdx.x&63;
  int i = blockIdx.x*4 + wave;
  if (i >= N_NODE) return;
  int beg = rowptr[i], end = rowptr[i+1];
  float2 accA = {0.f,0.f}, accB = {0.f,0.f};
  if (end > beg){
    float mA = -1e30f, mB = -1e30f;
    for (int k=beg+lane; k<end; k+=64){
      int t = idx[k];
      mA = fmaxf(mA, attA[t]); mB = fmaxf(mB, attB[t]);
    }
    mA = waveMax(mA); mB = waveMax(mB);
    float zA = 0.f, zB = 0.f;
    for (int k=beg+lane; k<end; k+=64){
      int t = idx[k];
      zA += __expf(attA[t]-mA); zB += __expf(attB[t]-mB);
    }
    zA = waveSum(zA); zB = waveSum(zB);
    float izA = 1.f/zA, izB = 1.f/zB;
    for (int k=beg; k<end; ++k){
      int t = idx[k];
      int c = cols[t];
      float2 u  = *(const float2*)(tri + (size_t)t*DIM + lane*2);
      float2 fA = *(const float2*)(out + (size_t)c*OUTD + inA + lane*2);
      float2 fB = *(const float2*)(out + (size_t)c*OUTD + inB + lane*2);
      float dA = waveSum(fA.x*u.x + fA.y*u.y);
      float dB = waveSum(fB.x*u.x + fB.y*u.y);
      float wA = __expf(attA[t]-mA)*izA;
      float wB = __expf(attB[t]-mB)*izB;
      accA.x += wA*(fA.x - 2.f*dA*u.x); accA.y += wA*(fA.y - 2.f*dA*u.y);
      accB.x += wB*(fB.x - 2.f*dB*u.x); accB.y += wB*(fB.y - 2.f*dB*u.y);
    }
  }
  float2 oA = { tanhf(accA.x), tanhf(accA.y) };
  float2 oB = { tanhf(accB.x), tanhf(accB.y) };
  *(float2*)(out + (size_t)i*OUTD + outA + lane*2) = oA;
  *(float2*)(out + (size_t)i*OUTD + outB + lane*2) = oB;
}

// ---------------- pack E ----------------
__global__ __launch_bounds__(256) void k_packE(const float* __restrict__ out, __bf16* __restrict__ Ep, float* __restrict__ esq){
  int wave = threadIdx.x>>6, lane = threadIdx.x&63;
  int j = blockIdx.x*4 + wave;
  if (j >= EPAD) return;
  int jt = j>>7, r = j&127;
  __bf16* tb = Ep + (size_t)jt*TILE_ELEMS;
  float ss = 0.f;
  for (int c=lane; c<96; c+=64){
    int kb = c>>2, q = c&3;
    bf16x8 o;
    if (j < N_NODE){
      const float* src = out + (size_t)j*OUTD + c*8;
#pragma unroll
      for (int e=0;e<8;e++){ float v = src[e]; ss += v*v; o[e] = (__bf16)v; }
    } else {
#pragma unroll
      for (int e=0;e<8;e++) o[e] = (__bf16)0.f;
    }
    *(bf16x8*)(tb + kb*KBLK_ELEMS + swz_off(r, q)) = o;
  }
  ss = waveSum(ss);
  if (lane==0) esq[j] = (j < N_NODE) ? ss : 0.f;
}

__global__ __launch_bounds__(256) void k_packA(const int* __restrict__ pairs, const __bf16* __restrict__ Ep,
    const float* __restrict__ out, const float* __restrict__ esq,
    __bf16* __restrict__ Ap, float* __restrict__ asq, float* __restrict__ pos){
  int wave = threadIdx.x>>6, lane = threadIdx.x&63;
  int p = blockIdx.x*4 + wave;
  if (p >= BATCH) return;
  int l = pairs[2*p], r = pairs[2*p+1];
  float ss = 0.f;
#pragma unroll
  for (int c=0;c<12;c++){
    int d = c*64 + lane;
    float dl = out[(size_t)l*OUTD + d], dr = out[(size_t)r*OUTD + d];
    ss += (dl-dr)*(dl-dr);
  }
  ss = waveSum(ss);
  if (lane==0){ pos[p] = ss; asq[p] = esq[l]; asq[p+BATCH] = esq[r]; }
  int lt = l>>7, lr = l&127;
  int rt2 = r>>7, rr = r&127;
  int p0t = p>>7, p0r = p&127;
  int p1t = (p+BATCH)>>7, p1r = (p+BATCH)&127;
  for (int c=lane; c<96; c+=64){
    int kb = c>>2, q = c&3;
    bf16x8 vl = *(const bf16x8*)(Ep + (size_t)lt*TILE_ELEMS + kb*KBLK_ELEMS + swz_off(lr, q));
    *(bf16x8*)(Ap + (size_t)p0t*TILE_ELEMS + kb*KBLK_ELEMS + swz_off(p0r, q)) = vl;
    bf16x8 vr = *(const bf16x8*)(Ep + (size_t)rt2*TILE_ELEMS + kb*KBLK_ELEMS + swz_off(rr, q));
    *(bf16x8*)(Ap + (size_t)p1t*TILE_ELEMS + kb*KBLK_ELEMS + swz_off(p1r, q)) = vr;
  }
}

// ---------------- GEMM: pass1 = moments(+optional neg16 store); pass2 = fallback exp ----------------
__global__ __launch_bounds__(256) void k_gemm(
    const __bf16* __restrict__ Ap, const __bf16* __restrict__ Ep,
    const float* __restrict__ asq, const float* __restrict__ esq,
    const float* __restrict__ pos, const int* __restrict__ pairs,
    float* __restrict__ rs1, float* __restrict__ rs2, float* __restrict__ rmin,
    const float* __restrict__ CC, const float* __restrict__ AL,
    float* __restrict__ rexp, _Float16* __restrict__ neg16, int pass)
{
  __shared__ __bf16 sA[KBLK_ELEMS];
  __shared__ __bf16 sB[KBLK_ELEMS];
  __shared__ float red[768];   // [3][il*2+wj]
  int tid = threadIdx.x;

  int wave = tid>>6, lane = tid&63, quad = lane>>4, l16 = lane&15;
  int bi = blockIdx.x, bj = blockIdx.y;
  int wi = wave>>1, wj = wave&1;

  const __bf16* Asrc = Ap + (size_t)bi*TILE_ELEMS;
  const __bf16* Bsrc = Ep + (size_t)bj*TILE_ELEMS;

  int a_off[4], b_off[4];
#pragma unroll
  for (int rt=0; rt<4; ++rt){ int row = wi*64 + rt*16 + l16; a_off[rt] = swz_off(row, quad); }
#pragma unroll
  for (int ct=0; ct<4; ++ct){ int row = wj*64 + ct*16 + l16; b_off[ct] = swz_off(row, quad); }

  const __bf16* gsrc = (wave<2 ? Asrc : Bsrc);
  __bf16* ldsb = (wave<2 ? sA : sB);
  int half = (wave&1)*2048;

  const f32x4 zf = {0.f,0.f,0.f,0.f};
  f32x4 acc[4][4];
#pragma unroll
  for (int rt=0; rt<4; ++rt)
#pragma unroll
    for (int ct=0; ct<4; ++ct) acc[rt][ct] = zf;

  for (int kb=0; kb<24; ++kb){
    __syncthreads();
    const __bf16* g = gsrc + kb*KBLK_ELEMS + half + lane*8;
#pragma unroll
    for (int s=0; s<4; ++s)
      gl2lds16(g + s*512, ldsb + half + s*512);
    __syncthreads();
    bf16x8 af[4], bf[4];
#pragma unroll
    for (int rt=0; rt<4; ++rt) af[rt] = *(const bf16x8*)(sA + a_off[rt]);
#pragma unroll
    for (int ct=0; ct<4; ++ct) bf[ct] = *(const bf16x8*)(sB + b_off[ct]);
#pragma unroll
    for (int rt=0; rt<4; ++rt)
#pragma unroll
      for (int ct=0; ct<4; ++ct)
        acc[rt][ct] = __builtin_amdgcn_mfma_f32_16x16x32_bf16(af[rt], bf[ct], acc[rt][ct], 0,0,0);
  }

  // ---- epilogue ----
  int jbase = bj*128 + wj*64;
  float esqv[4]; bool val[4]; int jcol[4];
#pragma unroll
  for (int ct=0; ct<4; ++ct){
    jcol[ct] = jbase + ct*16 + l16;
    val[ct] = jcol[ct] < N_NODE;
    esqv[ct] = esq[jcol[ct]];
  }

  size_t nb = negBase(bi, bj, wave, lane);

  if (pass == 1){
#pragma unroll
    for (int rt=0; rt<4; ++rt){
      _Float16 h16[16];
#pragma unroll
      for (int reg=0; reg<4; ++reg){
        int il = wi*64 + rt*16 + quad*4 + reg;
        int i  = bi*128 + il;
        int p  = i & (BATCH-1);
        int li = pairs[2*p], ri = pairs[2*p+1];
        float av = asq[i];
        float s=0.f, q=0.f, mn=1e30f;
#pragma unroll
        for (int ct=0; ct<4; ++ct){
          float neg = (av + esqv[ct]) - 2.f*acc[rt][ct][reg];
          s += neg;
          q = fmaf(neg, neg, q);
          bool bad = (jcol[ct]==li) | (jcol[ct]==ri) | (!val[ct]);
          mn = fminf(mn, bad ? 1e30f : neg);
          h16[reg*4+ct] = (_Float16)neg;
        }
#pragma unroll
        for (int m=1;m<16;m<<=1){
          s += __shfl_xor(s,m,64); q += __shfl_xor(q,m,64);
          mn = fminf(mn, __shfl_xor(mn,m,64));
        }
        if (l16 == 0){
          red[il*2+wj] = s; red[256 + il*2+wj] = q; red[512 + il*2+wj] = mn;
        }
      }
      if (neg16){
        *(half8*)(neg16 + nb + rt*16)     = *(half8*)&h16[0];
        *(half8*)(neg16 + nb + rt*16 + 8) = *(half8*)&h16[8];
      }
    }
    __syncthreads();
    if (tid < 128){
      int i = bi*128 + tid;
      atomicAdd(rs1+i, red[tid*2] + red[tid*2+1]);
      atomicAdd(rs2+i, red[256 + tid*2] + red[256 + tid*2+1]);
      atomicMinF(rmin+i, fminf(red[512 + tid*2], red[512 + tid*2+1]));
    }
  } else {
#pragma unroll
    for (int rt=0; rt<4; ++rt){
#pragma unroll
      for (int reg=0; reg<4; ++reg){
        int il = wi*64 + rt*16 + quad*4 + reg;
        int i  = bi*128 + il;
        int p  = i & (BATCH-1);
        int li = pairs[2*p], ri = pairs[2*p+1];
        float av = asq[i];
        float C = CC[i], A = AL[i];
        float s = 0.f;
#pragma unroll
        for (int ct=0; ct<4; ++ct){
          float neg = (av + esqv[ct]) - 2.f*acc[rt][ct][reg];
          bool bad = (jcol[ct]==li) | (jcol[ct]==ri) | (!val[ct]);
          s += bad ? 0.f : __expf(fmaf(-A, neg, C));
        }
#pragma unroll
        for (int m=1;m<16;m<<=1) s += __shfl_xor(s,m,64);
        if (l16 == 0) red[il*2+wj] = s;
      }
    }
    __syncthreads();
    if (tid < 128){
      int i = bi*128 + tid;
      atomicAdd(rexp+i, red[tid*2] + red[tid*2+1]);
    }
  }
}

// ---------------- streaming pass 2 (reads stored fp16 neg) ----------------
__global__ __launch_bounds__(256) void k_p2s(
    const _Float16* __restrict__ neg16, const float* __restrict__ CC, const float* __restrict__ AL,
    const int* __restrict__ pairs, float* __restrict__ rexp)
{
  __shared__ float red[256];
  int tid = threadIdx.x;
  int wave = tid>>6, lane = tid&63, quad = lane>>4, l16 = lane&15;
  int bi = blockIdx.x, bj = blockIdx.y;
  int wi = wave>>1, wj = wave&1;
  int jbase = bj*128 + wj*64;
  bool val[4]; int jcol[4];
#pragma unroll
  for (int ct=0; ct<4; ++ct){
    jcol[ct] = jbase + ct*16 + l16;
    val[ct] = jcol[ct] < N_NODE;
  }
  size_t nb = negBase(bi, bj, wave, lane);
#pragma unroll
  for (int rt=0; rt<4; ++rt){
    half8 v0 = *(const half8*)(neg16 + nb + rt*16);
    half8 v1 = *(const half8*)(neg16 + nb + rt*16 + 8);
    _Float16 h16[16];
    *(half8*)&h16[0] = v0; *(half8*)&h16[8] = v1;
#pragma unroll
    for (int reg=0; reg<4; ++reg){
      int il = wi*64 + rt*16 + quad*4 + reg;
      int i  = bi*128 + il;
      int p  = i & (BATCH-1);
      int li = pairs[2*p], ri = pairs[2*p+1];
      float C = CC[i], A = AL[i];
      float s = 0.f;
#pragma unroll
      for (int ct=0; ct<4; ++ct){
        float neg = (float)h16[reg*4+ct];
        bool bad = (jcol[ct]==li) | (jcol[ct]==ri) | (!val[ct]);
        s += bad ? 0.f : __expf(fmaf(-A, neg, C));
      }
#pragma unroll
      for (int m=1;m<16;m<<=1) s += __shfl_xor(s,m,64);
      if (l16 == 0) red[il*2+wj] = s;
    }
  }
  __syncthreads();
  if (tid < 128){
    int i = bi*128 + tid;
    atomicAdd(rexp+i, red[tid*2] + red[tid*2+1]);
  }
}

// ---------------- per-row special-column dots (exact index masking) ----------------
__global__ __launch_bounds__(256) void k_corr(
    const int* __restrict__ pairs, const __bf16* __restrict__ Ap, const __bf16* __restrict__ Ep,
    const float* __restrict__ asq, const float* __restrict__ esq,
    float* __restrict__ negl, float* __restrict__ negr)
{
  int wave = threadIdx.x>>6, lane = threadIdx.x&63;
  int i = blockIdx.x*4 + wave;
  if (i >= NROWA) return;
  int p = i & (BATCH-1);
  int li = pairs[2*p], ri = pairs[2*p+1];
  const __bf16* Ar = Ap + (size_t)(i>>7)*TILE_ELEMS;  int ra = i&127;
  const __bf16* E1 = Ep + (size_t)(li>>7)*TILE_ELEMS; int r1 = li&127;
  const __bf16* E2 = Ep + (size_t)(ri>>7)*TILE_ELEMS; int r2 = ri&127;
  float d1=0.f, d2=0.f;
  for (int c=lane; c<96; c+=64){
    int kb = c>>2, q = c&3;
    bf16x8 a  = *(const bf16x8*)(Ar + kb*KBLK_ELEMS + swz_off(ra, q));
    bf16x8 e1 = *(const bf16x8*)(E1 + kb*KBLK_ELEMS + swz_off(r1, q));
    bf16x8 e2 = *(const bf16x8*)(E2 + kb*KBLK_ELEMS + swz_off(r2, q));
#pragma unroll
    for (int e=0;e<8;e++){
      d1 = fmaf((float)a[e], (float)e1[e], d1);
      d2 = fmaf((float)a[e], (float)e2[e], d2);
    }
  }
  d1 = waveSum(d1); d2 = waveSum(d2);
  if (lane==0){
    float av = asq[i];
    negl[i] = av + esq[li] - 2.f*d1;
    negr[i] = av + esq[ri] - 2.f*d2;
  }
}

// ---------------- stats: combine moments + corrections -> CC, AL, MM, REXP base ----------------
__global__ __launch_bounds__(256) void k_stats(
    const float* __restrict__ rs1, const float* __restrict__ rs2, const float* __restrict__ rmin,
    const float* __restrict__ negl, const float* __restrict__ negr,
    const float* __restrict__ asq, const float* __restrict__ pos, const int* __restrict__ pairs,
    float* __restrict__ MM, float* __restrict__ CC, float* __restrict__ AL, float* __restrict__ rexp)
{
  int i = blockIdx.x*256 + threadIdx.x;
  if (i >= NROWA) return;
  int p = i & (BATCH-1);
  int li = pairs[2*p], ri = pairs[2*p+1];
  float K = pos[p] + GAMMA_C;
  float av = asq[i];
  float S1 = rs1[i] - (float)PADN*av;
  float S2 = rs2[i] - (float)PADN*av*av;
  float nl = negl[i], nr = negr[i];
  float Sx, Sxx, mx, maskedExp;
  const float invN = 1.f/(float)N_NODE;
  if (li != ri){
    Sx  = -(S1 - nl - nr) - 2.f*K;
    Sxx = (S2 - nl*nl - nr*nr) + 2.f*K*K;
    mx  = fmaxf(K - rmin[i], 0.f);
    float mu = K + Sx*invN;
    float m2 = Sx*invN;
    float var = Sxx*invN - m2*m2;
    float sd = sqrtf(fmaxf(var, 1e-30f));
    float M = LAMB_C*(mx-mu)/sd + TAU_C;
    MM[i] = M; CC[i] = LAMB_C*(K-mu)/sd + TAU_C - M; AL[i] = LAMB_C/sd;
    rexp[i] = 2.f*__expf(LAMB_C*(0.f-mu)/sd + TAU_C - M);
  } else {
    float lossm = nl - K;       // fct = -1
    float x = lossm - K;
    Sx  = -(S1 - nl) + x;
    Sxx = (S2 - nl*nl) + x*x;
    mx  = fmaxf(K - rmin[i], lossm);
    float mu = K + Sx*invN;
    float m2 = Sx*invN;
    float var = Sxx*invN - m2*m2;
    float sd = sqrtf(fmaxf(var, 1e-30f));
    float M = LAMB_C*(mx-mu)/sd + TAU_C;
    MM[i] = M; CC[i] = LAMB_C*(K-mu)/sd + TAU_C - M; AL[i] = LAMB_C/sd;
    rexp[i] = __expf(LAMB_C*(lossm-mu)/sd + TAU_C - M);
  }
}

__global__ __launch_bounds__(256) void k_final(const float* __restrict__ mm, const float* __restrict__ rexp, float* __restrict__ out){
  __shared__ float red[256];
  float s = 0.f;
  for (int i=threadIdx.x; i<NROWA; i+=256) s += mm[i] + logf(rexp[i]);
  red[threadIdx.x] = s; __syncthreads();
  for (int st=128; st>0; st>>=1){ if (threadIdx.x<st) red[threadIdx.x]+=red[threadIdx.x+st]; __syncthreads(); }
  if (threadIdx.x==0) out[0] = red[0]*(1.f/BATCH);
}

extern "C" void kernel_launch(void* const* d_in, const int* in_sizes, int n_in,
                              void* d_out, int out_size, void* d_ws, size_t ws_size,
                              hipStream_t stream) {
  const int*   pairs   = (const int*)d_in[0];
  const int*   ent_adj = (const int*)d_in[1];
  const int*   rel_adj = (const int*)d_in[2];
  const int*   adj     = (const int*)d_in[3];
  const int*   r_index = (const int*)d_in[4];
  const float* r_val   = (const float*)d_in[5];
  const float* ent_emb = (const float*)d_in[7];
  const float* rel_emb = (const float*)d_in[8];
  const float* attn_e  = (const float*)d_in[9];
  const float* attn_r  = (const float*)d_in[10];

  char* base = (char*)d_ws;
  size_t off = 0;
  auto take = [&](size_t bytes)->char*{
    char* p = base + off;
    off = (off + bytes + 511) & ~(size_t)511;
    return p;
  };
  float* OUT  = (float*)take((size_t)N_NODE*OUTD*4);   // 92.16 MB
  char*  TRIB = take((size_t)N_TRI*DIM*4);             // 102.4 MB, reused after GAT
  float* TRI  = (float*)TRIB;
  float* ATT4 = (float*)take((size_t)4*N_TRI*4);
  int* RP_E  = (int*)take((size_t)(N_NODE+1)*4);
  int* RP_R  = (int*)take((size_t)(N_NODE+1)*4);
  int* RP_A  = (int*)take((size_t)(N_NODE+1)*4);
  int* IDX_E = (int*)take((size_t)N_TRI*4);
  int* IDX_R = (int*)take((size_t)N_TRI*4);
  int* IDX_A = (int*)take((size_t)N_TRI*4);
  int* CNT6  = (int*)take((size_t)6*N_NODE*4);
  int* CNT_E = CNT6,            *CNT_R = CNT6 + N_NODE,   *CNT_A = CNT6 + 2*N_NODE;
  int* CUR_E = CNT6 + 3*N_NODE, *CUR_R = CNT6 + 4*N_NODE, *CUR_A = CNT6 + 5*N_NODE;

  // optional NEG16 buffer (fast path) at the tail of the first region
  _Float16* NEG16 = (_Float16*)(base + off);
  size_t needFast = off + (size_t)NROWA*EPAD*2;
  bool fast = (ws_size >= needFast);

  // overlay on TRI block (dead after GAT layers)
  size_t roff = 0;
  auto take2 = [&](size_t bytes)->char*{
    char* p = TRIB + roff;
    roff = (roff + bytes + 511) & ~(size_t)511;
    return p;
  };
  __bf16* EP    = (__bf16*)take2((size_t)NTILE_E*TILE_ELEMS*2); // 46.2 MB packed E
  float*  ESQ   = (float*)take2((size_t)EPAD*4);
  __bf16* AP    = (__bf16*)take2((size_t)NTILE_A*TILE_ELEMS*2); // 6.3 MB packed A
  float*  ASQ   = (float*)take2((size_t)NROWA*4);
  float*  POS   = (float*)take2((size_t)BATCH*4);
  float*  RS1   = (float*)take2((size_t)NROWA*4);
  float*  RS2   = (float*)take2((size_t)NROWA*4);
  float*  RMIN  = (float*)take2((size_t)NROWA*4);
  float*  NEGL  = (float*)take2((size_t)NROWA*4);
  float*  NEGR  = (float*)take2((size_t)NROWA*4);
  float*  MM    = (float*)take2((size_t)NROWA*4);
  float*  CCv   = (float*)take2((size_t)NROWA*4);
  float*  ALv   = (float*)take2((size_t)NROWA*4);
  float*  REXP  = (float*)take2((size_t)NROWA*4);

  // ---- init ----
  k_fill<<<192,256,0,stream>>>((float*)CNT6, (long)6*N_NODE, 0.f);

  // ---- CSR builds ----
  k_hist<<<782,256,0,stream>>>(ent_adj, CNT_E);
  k_hist<<<782,256,0,stream>>>(rel_adj, CNT_R);
  k_hist<<<782,256,0,stream>>>(adj,     CNT_A);
  k_scan3<<<3,256,0,stream>>>(CNT_E, RP_E, CNT_R, RP_R, CNT_A, RP_A, N_NODE);
  k_place<<<782,256,0,stream>>>(ent_adj, ent_adj+N_TRI, RP_E, CUR_E, IDX_E, 1);
  k_place<<<782,256,0,stream>>>(rel_adj, rel_adj+N_TRI, RP_R, CUR_R, IDX_R, 1);
  k_place<<<782,256,0,stream>>>(adj,     (const int*)0, RP_A, CUR_A, IDX_A, 0);

  // ---- feature pipeline ----
  k_feat0<<<7500,256,0,stream>>>(RP_E, IDX_E, RP_R, IDX_R, ent_emb, rel_emb, OUT);
  k_trinorm<<<50000,256,0,stream>>>(r_index+N_TRI, r_val, rel_emb, TRI, attn_e, attn_r, ATT4);
  k_gat<<<7500,256,0,stream>>>(RP_A, IDX_A, adj+N_TRI, TRI,
                               ATT4 + 0*N_TRI, ATT4 + 2*N_TRI, OUT, 0, 128, 384, 512);
  k_gat<<<7500,256,0,stream>>>(RP_A, IDX_A, adj+N_TRI, TRI,
                               ATT4 + 1*N_TRI, ATT4 + 3*N_TRI, OUT, 128, 256, 512, 640);

  // ---- loss prep ----
  k_packE<<<7520,256,0,stream>>>(OUT, EP, ESQ);
  k_packA<<<512,256,0,stream>>>(pairs, EP, OUT, ESQ, AP, ASQ, POS);
  k_fill<<<16,256,0,stream>>>(RS1, (long)NROWA, 0.f);
  k_fill<<<16,256,0,stream>>>(RS2, (long)NROWA, 0.f);
  k_fill<<<16,256,0,stream>>>(RMIN,(long)NROWA, 1e30f);

  // ---- pass 1: GEMM + moments (+neg16 store on fast path) ----
  dim3 gg(NTILE_A, NTILE_E, 1);
  k_gemm<<<gg,256,0,stream>>>(AP, EP, ASQ, ESQ, POS, pairs,
                              RS1, RS2, RMIN, CCv, ALv, REXP,
                              fast ? NEG16 : (_Float16*)nullptr, 1);
  k_corr<<<1024,256,0,stream>>>(pairs, AP, EP, ASQ, ESQ, NEGL, NEGR);
  k_stats<<<16,256,0,stream>>>(RS1, RS2, RMIN, NEGL, NEGR, ASQ, POS, pairs,
                               MM, CCv, ALv, REXP);

  // ---- pass 2 ----
  if (fast){
    k_p2s<<<gg,256,0,stream>>>(NEG16, CCv, ALv, pairs, REXP);
  } else {
    k_gemm<<<gg,256,0,stream>>>(AP, EP, ASQ, ESQ, POS, pairs,
                                RS1, RS2, RMIN, CCv, ALv, REXP,
                                (_Float16*)nullptr, 2);
  }
  k_final<<<1,256,0,stream>>>(MM, REXP, (float*)d_out);
}

// Round 6
// 1210.393 us; speedup vs baseline: 1.0111x; 1.0111x over previous
//
#include <hip/hip_runtime.h>
#include <hip/hip_bf16.h>
#include <math.h>

#define N_NODE 30000
#define N_TRI  200000
#define DIM    128
#define OUTD   768
#define BATCH  2048
#define NROWA  4096
#define EPAD   30080   // 235*128
#define PADN   80      // EPAD - N_NODE
#define NTILE_E 235
#define NTILE_A 32
#define TILE_ELEMS (128*OUTD)
#define KBLK_ELEMS (128*32)
#define GAMMA_C 3.0f
#define LAMB_C  30.0f
#define TAU_C   10.0f

typedef __attribute__((ext_vector_type(8))) __bf16 bf16x8;
typedef __attribute__((ext_vector_type(2))) __bf16 bf16x2;
typedef __attribute__((ext_vector_type(8))) _Float16 half8;
typedef __attribute__((ext_vector_type(4))) float f32x4;

__device__ __forceinline__ float waveSum(float v){
#pragma unroll
  for (int m=1;m<64;m<<=1) v += __shfl_xor(v, m, 64);
  return v;
}
__device__ __forceinline__ float waveMax(float v){
#pragma unroll
  for (int m=1;m<64;m<<=1) v = fmaxf(v, __shfl_xor(v, m, 64));
  return v;
}

__device__ __forceinline__ void atomicMinF(float* a, float v){
  if (v >= 0.f) atomicMin((int*)a, __float_as_int(v));
  else          atomicMax((unsigned int*)a, __float_as_uint(v));
}

__device__ __forceinline__ void gl2lds16(const void* g, void* l){
  __builtin_amdgcn_global_load_lds(
      (const __attribute__((address_space(1))) char*)g,
      (__attribute__((address_space(3))) char*)l, 16, 0, 0);
}

__device__ __forceinline__ int swz_off(int r, int q){
  return r*32 + ((q ^ ((r>>1)&3))<<3);
}

// ---------------- fill ----------------
__global__ void k_fill(float* __restrict__ p, long n, float v){
  long i = (long)blockIdx.x*blockDim.x + threadIdx.x;
  long st = (long)gridDim.x*blockDim.x;
  for (; i<n; i+=st) p[i]=v;
}

// ---------------- CSR build ----------------
__global__ __launch_bounds__(256) void k_hist(const int* __restrict__ rows, int* __restrict__ cnt){
  int t = blockIdx.x*256 + threadIdx.x;
  if (t < N_TRI) atomicAdd(&cnt[rows[t]], 1);
}

__global__ __launch_bounds__(256) void k_scan3(
    const int* __restrict__ c0, int* __restrict__ r0,
    const int* __restrict__ c1, int* __restrict__ r1,
    const int* __restrict__ c2, int* __restrict__ r2, int n){
  const int* cnt = blockIdx.x==0 ? c0 : (blockIdx.x==1 ? c1 : c2);
  int* rp        = blockIdx.x==0 ? r0 : (blockIdx.x==1 ? r1 : r2);
  __shared__ int buf[256];
  __shared__ int carry;
  if (threadIdx.x==0) carry = 0;
  __syncthreads();
  for (int base=0; base<n; base+=256){
    int i = base + threadIdx.x;
    int v = (i<n) ? cnt[i] : 0;
    buf[threadIdx.x] = v;
    __syncthreads();
    for (int off=1; off<256; off<<=1){
      int t = (threadIdx.x>=off) ? buf[threadIdx.x-off] : 0;
      __syncthreads();
      buf[threadIdx.x] += t;
      __syncthreads();
    }
    if (i<n) rp[i] = carry + buf[threadIdx.x] - v;
    int tot = buf[255];
    __syncthreads();
    if (threadIdx.x==0) carry += tot;
    __syncthreads();
  }
  if (threadIdx.x==0) rp[n] = carry;
}

__global__ __launch_bounds__(256) void k_place(const int* __restrict__ rows, const int* __restrict__ vals,
                        const int* __restrict__ rowptr, int* __restrict__ cur, int* __restrict__ idx, int mode){
  int t = blockIdx.x*256 + threadIdx.x;
  if (t < N_TRI){
    int r = rows[t];
    int p = atomicAdd(&cur[r], 1);
    idx[rowptr[r] + p] = mode ? vals[t] : t;
  }
}

// ---------------- fused sparse means + tanh ----------------
__global__ __launch_bounds__(256) void k_feat0(
    const int* __restrict__ rpE, const int* __restrict__ idxE,
    const int* __restrict__ rpR, const int* __restrict__ idxR,
    const float* __restrict__ ent_emb, const float* __restrict__ rel_emb,
    float* __restrict__ out){
  int wave = threadIdx.x>>6, lane = threadIdx.x&63;
  int i = blockIdx.x*4 + wave;
  if (i >= N_NODE) return;
  int bE = rpE[i], eE = rpE[i+1];
  int bR = rpR[i], eR = rpR[i+1];
  float2 aE = {0.f,0.f}, aR = {0.f,0.f};
  for (int k=bE; k<eE; ++k){
    int c = idxE[k];
    float2 v = *(const float2*)(ent_emb + (size_t)c*DIM + lane*2);
    aE.x += v.x; aE.y += v.y;
  }
  for (int k=bR; k<eR; ++k){
    int c = idxR[k];
    float2 v = *(const float2*)(rel_emb + (size_t)c*DIM + lane*2);
    aR.x += v.x; aR.y += v.y;
  }
  float ie = 1.f/fmaxf((float)(eE-bE), 1.f);
  float ir = 1.f/fmaxf((float)(eR-bR), 1.f);
  float2 oE = { tanhf(aE.x*ie), tanhf(aE.y*ie) };
  float2 oR = { tanhf(aR.x*ir), tanhf(aR.y*ir) };
  *(float2*)(out + (size_t)i*OUTD +   0 + lane*2) = oE;
  *(float2*)(out + (size_t)i*OUTD + 384 + lane*2) = oR;
}

// ---------------- tri_rel direct + norm(bf16 store) + att logits ----------------
__global__ __launch_bounds__(256) void k_trinorm(
    const int* __restrict__ ridx1, const float* __restrict__ rval,
    const float* __restrict__ rel_emb,
    __bf16* __restrict__ tri, const float* __restrict__ attnE,
    const float* __restrict__ attnR, float* __restrict__ att4){
  __shared__ float ak[4][DIM];
  int tid = threadIdx.x;
  for (int idx=tid; idx<4*DIM; idx+=256){
    int k = idx>>7, d = idx&127;
    ak[k][d] = (k<2) ? attnE[k*DIM + d] : attnR[(k-2)*DIM + d];
  }
  __syncthreads();
  int wave = tid>>6, lane = tid&63;
  int t = blockIdx.x*4 + wave;
  if (t >= N_TRI) return;
  int rr = ridx1[t];
  float rv = rval[t];
  float2 v = *(const float2*)(rel_emb + (size_t)rr*DIM + lane*2);
  v.x *= rv; v.y *= rv;
  float ss = waveSum(v.x*v.x + v.y*v.y);
  float inv = 1.f/fmaxf(sqrtf(ss), 1e-12f);
  v.x *= inv; v.y *= inv;
  bf16x2 b; b[0] = (__bf16)v.x; b[1] = (__bf16)v.y;
  *(bf16x2*)(tri + (size_t)t*DIM + lane*2) = b;
#pragma unroll
  for (int k=0;k<4;k++){
    float p = waveSum(v.x*ak[k][lane*2] + v.y*ak[k][lane*2+1]);
    if (lane==0) att4[(size_t)k*N_TRI + t] = p;
  }
}

// ---------------- fused GAT layer (both branches), bf16 tri ----------------
__global__ __launch_bounds__(256) void k_gat(
    const int* __restrict__ rowptr, const int* __restrict__ idx, const int* __restrict__ cols,
    const __bf16* __restrict__ tri,
    const float* __restrict__ attA, const float* __restrict__ attB,
    float* __restrict__ out, int inA, int outA, int inB, int outB){
  int wave = threadIdx.x>>6, lane = threadIdx.x&63;
  int i = blockIdx.x*4 + wave;
  if (i >= N_NODE) return;
  int beg = rowptr[i], end = rowptr[i+1];
  float2 accA = {0.f,0.f}, accB = {0.f,0.f};
  if (end > beg){
    float mA = -1e30f, mB = -1e30f;
    for (int k=beg+lane; k<end; k+=64){
      int t = idx[k];
      mA = fmaxf(mA, attA[t]); mB = fmaxf(mB, attB[t]);
    }
    mA = waveMax(mA); mB = waveMax(mB);
    float zA = 0.f, zB = 0.f;
    for (int k=beg+lane; k<end; k+=64){
      int t = idx[k];
      zA += __expf(attA[t]-mA); zB += __expf(attB[t]-mB);
    }
    zA = waveSum(zA); zB = waveSum(zB);
    float izA = 1.f/zA, izB = 1.f/zB;
    for (int k=beg; k<end; ++k){
      int t = idx[k];
      int c = cols[t];
      bf16x2 ub = *(const bf16x2*)(tri + (size_t)t*DIM + lane*2);
      float2 u = { (float)ub[0], (float)ub[1] };
      float2 fA = *(const float2*)(out + (size_t)c*OUTD + inA + lane*2);
      float2 fB = *(const float2*)(out + (size_t)c*OUTD + inB + lane*2);
      float dA = waveSum(fA.x*u.x + fA.y*u.y);
      float dB = waveSum(fB.x*u.x + fB.y*u.y);
      float wA = __expf(attA[t]-mA)*izA;
      float wB = __expf(attB[t]-mB)*izB;
      accA.x += wA*(fA.x - 2.f*dA*u.x); accA.y += wA*(fA.y - 2.f*dA*u.y);
      accB.x += wB*(fB.x - 2.f*dB*u.x); accB.y += wB*(fB.y - 2.f*dB*u.y);
    }
  }
  float2 oA = { tanhf(accA.x), tanhf(accA.y) };
  float2 oB = { tanhf(accB.x), tanhf(accB.y) };
  *(float2*)(out + (size_t)i*OUTD + outA + lane*2) = oA;
  *(float2*)(out + (size_t)i*OUTD + outB + lane*2) = oB;
}

// ---------------- pack E ----------------
__global__ __launch_bounds__(256) void k_packE(const float* __restrict__ out, __bf16* __restrict__ Ep, float* __restrict__ esq){
  int wave = threadIdx.x>>6, lane = threadIdx.x&63;
  int j = blockIdx.x*4 + wave;
  if (j >= EPAD) return;
  int jt = j>>7, r = j&127;
  __bf16* tb = Ep + (size_t)jt*TILE_ELEMS;
  float ss = 0.f;
  for (int c=lane; c<96; c+=64){
    int kb = c>>2, q = c&3;
    bf16x8 o;
    if (j < N_NODE){
      const float* src = out + (size_t)j*OUTD + c*8;
#pragma unroll
      for (int e=0;e<8;e++){ float v = src[e]; ss += v*v; o[e] = (__bf16)v; }
    } else {
#pragma unroll
      for (int e=0;e<8;e++) o[e] = (__bf16)0.f;
    }
    *(bf16x8*)(tb + kb*KBLK_ELEMS + swz_off(r, q)) = o;
  }
  ss = waveSum(ss);
  if (lane==0) esq[j] = (j < N_NODE) ? ss : 0.f;
}

__global__ __launch_bounds__(256) void k_packA(const int* __restrict__ pairs, const __bf16* __restrict__ Ep,
    const float* __restrict__ out, const float* __restrict__ esq,
    __bf16* __restrict__ Ap, float* __restrict__ asq, float* __restrict__ pos){
  int wave = threadIdx.x>>6, lane = threadIdx.x&63;
  int p = blockIdx.x*4 + wave;
  if (p >= BATCH) return;
  int l = pairs[2*p], r = pairs[2*p+1];
  float ss = 0.f;
#pragma unroll
  for (int c=0;c<12;c++){
    int d = c*64 + lane;
    float dl = out[(size_t)l*OUTD + d], dr = out[(size_t)r*OUTD + d];
    ss += (dl-dr)*(dl-dr);
  }
  ss = waveSum(ss);
  if (lane==0){ pos[p] = ss; asq[p] = esq[l]; asq[p+BATCH] = esq[r]; }
  int lt = l>>7, lr = l&127;
  int rt2 = r>>7, rr = r&127;
  int p0t = p>>7, p0r = p&127;
  int p1t = (p+BATCH)>>7, p1r = (p+BATCH)&127;
  for (int c=lane; c<96; c+=64){
    int kb = c>>2, q = c&3;
    bf16x8 vl = *(const bf16x8*)(Ep + (size_t)lt*TILE_ELEMS + kb*KBLK_ELEMS + swz_off(lr, q));
    *(bf16x8*)(Ap + (size_t)p0t*TILE_ELEMS + kb*KBLK_ELEMS + swz_off(p0r, q)) = vl;
    bf16x8 vr = *(const bf16x8*)(Ep + (size_t)rt2*TILE_ELEMS + kb*KBLK_ELEMS + swz_off(rr, q));
    *(bf16x8*)(Ap + (size_t)p1t*TILE_ELEMS + kb*KBLK_ELEMS + swz_off(p1r, q)) = vr;
  }
}

// ---------------- GEMM: pass1 = moments (+optional neg16 store); pass2 = fallback exp ----------------
__global__ __launch_bounds__(256) void k_gemm(
    const __bf16* __restrict__ Ap, const __bf16* __restrict__ Ep,
    const float* __restrict__ asq, const float* __restrict__ esq,
    const float* __restrict__ pos, const int* __restrict__ pairs,
    float* __restrict__ rs1, float* __restrict__ rs2, float* __restrict__ rmin,
    const float* __restrict__ CC, const float* __restrict__ AL,
    float* __restrict__ rexp, _Float16* __restrict__ neg16, int pass)
{
  __shared__ __bf16 sA[KBLK_ELEMS];
  __shared__ __bf16 sB[KBLK_ELEMS];
  __shared__ float red[768];
  int tid = threadIdx.x;

  int wave = tid>>6, lane = tid&63, quad = lane>>4, l16 = lane&15;
  int bi = blockIdx.x, bj = blockIdx.y;
  int wi = wave>>1, wj = wave&1;

  const __bf16* Asrc = Ap + (size_t)bi*TILE_ELEMS;
  const __bf16* Bsrc = Ep + (size_t)bj*TILE_ELEMS;

  int a_off[4], b_off[4];
#pragma unroll
  for (int rt=0; rt<4; ++rt){ int row = wi*64 + rt*16 + l16; a_off[rt] = swz_off(row, quad); }
#pragma unroll
  for (int ct=0; ct<4; ++ct){ int row = wj*64 + ct*16 + l16; b_off[ct] = swz_off(row, quad); }

  const __bf16* gsrc = (wave<2 ? Asrc : Bsrc);
  __bf16* ldsb = (wave<2 ? sA : sB);
  int half = (wave&1)*2048;

  const f32x4 zf = {0.f,0.f,0.f,0.f};
  f32x4 acc[4][4];
#pragma unroll
  for (int rt=0; rt<4; ++rt)
#pragma unroll
    for (int ct=0; ct<4; ++ct) acc[rt][ct] = zf;

  for (int kb=0; kb<24; ++kb){
    __syncthreads();
    const __bf16* g = gsrc + kb*KBLK_ELEMS + half + lane*8;
#pragma unroll
    for (int s=0; s<4; ++s)
      gl2lds16(g + s*512, ldsb + half + s*512);
    __syncthreads();
    bf16x8 af[4], bf[4];
#pragma unroll
    for (int rt=0; rt<4; ++rt) af[rt] = *(const bf16x8*)(sA + a_off[rt]);
#pragma unroll
    for (int ct=0; ct<4; ++ct) bf[ct] = *(const bf16x8*)(sB + b_off[ct]);
#pragma unroll
    for (int rt=0; rt<4; ++rt)
#pragma unroll
      for (int ct=0; ct<4; ++ct)
        acc[rt][ct] = __builtin_amdgcn_mfma_f32_16x16x32_bf16(af[rt], bf[ct], acc[rt][ct], 0,0,0);
  }

  // ---- epilogue ----
  int jbase = bj*128 + wj*64;
  float esqv[4]; bool val[4]; int jcol[4];
#pragma unroll
  for (int ct=0; ct<4; ++ct){
    jcol[ct] = jbase + ct*16 + l16;
    val[ct] = jcol[ct] < N_NODE;
    esqv[ct] = esq[jcol[ct]];
  }

  size_t tIdx = (size_t)bi*NTILE_E + bj;

  if (pass == 1){
#pragma unroll
    for (int rt=0; rt<4; ++rt){
      _Float16 h16[16];
#pragma unroll
      for (int reg=0; reg<4; ++reg){
        int il = wi*64 + rt*16 + quad*4 + reg;
        int i  = bi*128 + il;
        int p  = i & (BATCH-1);
        int li = pairs[2*p], ri = pairs[2*p+1];
        float av = asq[i];
        float s=0.f, q=0.f, mn=1e30f;
#pragma unroll
        for (int ct=0; ct<4; ++ct){
          float neg = (av + esqv[ct]) - 2.f*acc[rt][ct][reg];
          s += neg;
          q = fmaf(neg, neg, q);
          bool bad = (jcol[ct]==li) | (jcol[ct]==ri) | (!val[ct]);
          mn = fminf(mn, bad ? 1e30f : neg);
          h16[reg*4+ct] = (_Float16)neg;
        }
#pragma unroll
        for (int m=1;m<16;m<<=1){
          s += __shfl_xor(s,m,64); q += __shfl_xor(q,m,64);
          mn = fminf(mn, __shfl_xor(mn,m,64));
        }
        if (l16 == 0){
          red[il*2+wj] = s; red[256 + il*2+wj] = q; red[512 + il*2+wj] = mn;
        }
      }
      if (neg16){
        _Float16* dst = neg16 + tIdx*16384 + ((size_t)(wave*4 + rt))*1024 + lane*16;
        *(half8*)(dst)     = *(half8*)&h16[0];
        *(half8*)(dst + 8) = *(half8*)&h16[8];
      }
    }
    __syncthreads();
    if (tid < 128){
      int i = bi*128 + tid;
      atomicAdd(rs1+i, red[tid*2] + red[tid*2+1]);
      atomicAdd(rs2+i, red[256 + tid*2] + red[256 + tid*2+1]);
      atomicMinF(rmin+i, fminf(red[512 + tid*2], red[512 + tid*2+1]));
    }
  } else {
#pragma unroll
    for (int rt=0; rt<4; ++rt){
#pragma unroll
      for (int reg=0; reg<4; ++reg){
        int il = wi*64 + rt*16 + quad*4 + reg;
        int i  = bi*128 + il;
        int p  = i & (BATCH-1);
        int li = pairs[2*p], ri = pairs[2*p+1];
        float av = asq[i];
        float C = CC[i], A = AL[i];
        float s = 0.f;
#pragma unroll
        for (int ct=0; ct<4; ++ct){
          float neg = (av + esqv[ct]) - 2.f*acc[rt][ct][reg];
          bool bad = (jcol[ct]==li) | (jcol[ct]==ri) | (!val[ct]);
          s += bad ? 0.f : __expf(fmaf(-A, neg, C));
        }
#pragma unroll
        for (int m=1;m<16;m<<=1) s += __shfl_xor(s,m,64);
        if (l16 == 0) red[il*2+wj] = s;
      }
    }
    __syncthreads();
    if (tid < 128){
      int i = bi*128 + tid;
      atomicAdd(rexp+i, red[tid*2] + red[tid*2+1]);
    }
  }
}

// ---------------- streaming pass 2 (reads stored fp16 neg) ----------------
__global__ __launch_bounds__(256) void k_p2s(
    const _Float16* __restrict__ neg16, const float* __restrict__ CC, const float* __restrict__ AL,
    const int* __restrict__ pairs, float* __restrict__ rexp)
{
  __shared__ float red[256];
  int tid = threadIdx.x;
  int wave = tid>>6, lane = tid&63, quad = lane>>4, l16 = lane&15;
  int bi = blockIdx.x, bj = blockIdx.y;
  int wi = wave>>1, wj = wave&1;
  int jbase = bj*128 + wj*64;
  bool val[4]; int jcol[4];
#pragma unroll
  for (int ct=0; ct<4; ++ct){
    jcol[ct] = jbase + ct*16 + l16;
    val[ct] = jcol[ct] < N_NODE;
  }
  size_t tIdx = (size_t)bi*NTILE_E + bj;
#pragma unroll
  for (int rt=0; rt<4; ++rt){
    const _Float16* src = neg16 + tIdx*16384 + ((size_t)(wave*4 + rt))*1024 + lane*16;
    half8 v0 = *(const half8*)(src);
    half8 v1 = *(const half8*)(src + 8);
    _Float16 h16[16];
    *(half8*)&h16[0] = v0; *(half8*)&h16[8] = v1;
#pragma unroll
    for (int reg=0; reg<4; ++reg){
      int il = wi*64 + rt*16 + quad*4 + reg;
      int i  = bi*128 + il;
      int p  = i & (BATCH-1);
      int li = pairs[2*p], ri = pairs[2*p+1];
      float C = CC[i], A = AL[i];
      float s = 0.f;
#pragma unroll
      for (int ct=0; ct<4; ++ct){
        float neg = (float)h16[reg*4+ct];
        bool bad = (jcol[ct]==li) | (jcol[ct]==ri) | (!val[ct]);
        s += bad ? 0.f : __expf(fmaf(-A, neg, C));
      }
#pragma unroll
      for (int m=1;m<16;m<<=1) s += __shfl_xor(s,m,64);
      if (l16 == 0) red[il*2+wj] = s;
    }
  }
  __syncthreads();
  if (tid < 128){
    int i = bi*128 + tid;
    atomicAdd(rexp+i, red[tid*2] + red[tid*2+1]);
  }
}

// ---------------- per-row special-column dots ----------------
__global__ __launch_bounds__(256) void k_corr(
    const int* __restrict__ pairs, const __bf16* __restrict__ Ap, const __bf16* __restrict__ Ep,
    const float* __restrict__ asq, const float* __restrict__ esq,
    float* __restrict__ negl, float* __restrict__ negr)
{
  int wave = threadIdx.x>>6, lane = threadIdx.x&63;
  int i = blockIdx.x*4 + wave;
  if (i >= NROWA) return;
  int p = i & (BATCH-1);
  int li = pairs[2*p], ri = pairs[2*p+1];
  const __bf16* Ar = Ap + (size_t)(i>>7)*TILE_ELEMS;  int ra = i&127;
  const __bf16* E1 = Ep + (size_t)(li>>7)*TILE_ELEMS; int r1 = li&127;
  const __bf16* E2 = Ep + (size_t)(ri>>7)*TILE_ELEMS; int r2 = ri&127;
  float d1=0.f, d2=0.f;
  for (int c=lane; c<96; c+=64){
    int kb = c>>2, q = c&3;
    bf16x8 a  = *(const bf16x8*)(Ar + kb*KBLK_ELEMS + swz_off(ra, q));
    bf16x8 e1 = *(const bf16x8*)(E1 + kb*KBLK_ELEMS + swz_off(r1, q));
    bf16x8 e2 = *(const bf16x8*)(E2 + kb*KBLK_ELEMS + swz_off(r2, q));
#pragma unroll
    for (int e=0;e<8;e++){
      d1 = fmaf((float)a[e], (float)e1[e], d1);
      d2 = fmaf((float)a[e], (float)e2[e], d2);
    }
  }
  d1 = waveSum(d1); d2 = waveSum(d2);
  if (lane==0){
    float av = asq[i];
    negl[i] = av + esq[li] - 2.f*d1;
    negr[i] = av + esq[ri] - 2.f*d2;
  }
}

// ---------------- stats ----------------
__global__ __launch_bounds__(256) void k_stats(
    const float* __restrict__ rs1, const float* __restrict__ rs2, const float* __restrict__ rmin,
    const float* __restrict__ negl, const float* __restrict__ negr,
    const float* __restrict__ asq, const float* __restrict__ pos, const int* __restrict__ pairs,
    float* __restrict__ MM, float* __restrict__ CC, float* __restrict__ AL, float* __restrict__ rexp)
{
  int i = blockIdx.x*256 + threadIdx.x;
  if (i >= NROWA) return;
  int p = i & (BATCH-1);
  int li = pairs[2*p], ri = pairs[2*p+1];
  float K = pos[p] + GAMMA_C;
  float av = asq[i];
  float S1 = rs1[i] - (float)PADN*av;
  float S2 = rs2[i] - (float)PADN*av*av;
  float nl = negl[i], nr = negr[i];
  float Sx, Sxx, mx;
  const float invN = 1.f/(float)N_NODE;
  if (li != ri){
    Sx  = -(S1 - nl - nr) - 2.f*K;
    Sxx = (S2 - nl*nl - nr*nr) + 2.f*K*K;
    mx  = fmaxf(K - rmin[i], 0.f);
    float mu = K + Sx*invN;
    float m2 = Sx*invN;
    float var = Sxx*invN - m2*m2;
    float sd = sqrtf(fmaxf(var, 1e-30f));
    float M = LAMB_C*(mx-mu)/sd + TAU_C;
    MM[i] = M; CC[i] = LAMB_C*(K-mu)/sd + TAU_C - M; AL[i] = LAMB_C/sd;
    rexp[i] = 2.f*__expf(LAMB_C*(0.f-mu)/sd + TAU_C - M);
  } else {
    float lossm = nl - K;
    float x = lossm - K;
    Sx  = -(S1 - nl) + x;
    Sxx = (S2 - nl*nl) + x*x;
    mx  = fmaxf(K - rmin[i], lossm);
    float mu = K + Sx*invN;
    float m2 = Sx*invN;
    float var = Sxx*invN - m2*m2;
    float sd = sqrtf(fmaxf(var, 1e-30f));
    float M = LAMB_C*(mx-mu)/sd + TAU_C;
    MM[i] = M; CC[i] = LAMB_C*(K-mu)/sd + TAU_C - M; AL[i] = LAMB_C/sd;
    rexp[i] = __expf(LAMB_C*(lossm-mu)/sd + TAU_C - M);
  }
}

__global__ __launch_bounds__(256) void k_final(const float* __restrict__ mm, const float* __restrict__ rexp, float* __restrict__ out){
  __shared__ float red[256];
  float s = 0.f;
  for (int i=threadIdx.x; i<NROWA; i+=256) s += mm[i] + logf(rexp[i]);
  red[threadIdx.x] = s; __syncthreads();
  for (int st=128; st>0; st>>=1){ if (threadIdx.x<st) red[threadIdx.x]+=red[threadIdx.x+st]; __syncthreads(); }
  if (threadIdx.x==0) out[0] = red[0]*(1.f/BATCH);
}

extern "C" void kernel_launch(void* const* d_in, const int* in_sizes, int n_in,
                              void* d_out, int out_size, void* d_ws, size_t ws_size,
                              hipStream_t stream) {
  const int*   pairs   = (const int*)d_in[0];
  const int*   ent_adj = (const int*)d_in[1];
  const int*   rel_adj = (const int*)d_in[2];
  const int*   adj     = (const int*)d_in[3];
  const int*   r_index = (const int*)d_in[4];
  const float* r_val   = (const float*)d_in[5];
  const float* ent_emb = (const float*)d_in[7];
  const float* rel_emb = (const float*)d_in[8];
  const float* attn_e  = (const float*)d_in[9];
  const float* attn_r  = (const float*)d_in[10];

  char* base = (char*)d_ws;
  size_t off = 0;
  auto take = [&](size_t bytes)->char*{
    char* p = base + off;
    off = (off + bytes + 511) & ~(size_t)511;
    return p;
  };
  // ---- persistent GEMM-phase region (first ~53 MB) ----
  __bf16* EP    = (__bf16*)take((size_t)NTILE_E*TILE_ELEMS*2); // 46.2 MB
  __bf16* AP    = (__bf16*)take((size_t)NTILE_A*TILE_ELEMS*2); // 6.3 MB
  float*  ESQ   = (float*)take((size_t)EPAD*4);
  float*  ASQ   = (float*)take((size_t)NROWA*4);
  float*  POS   = (float*)take((size_t)BATCH*4);
  float*  RS1   = (float*)take((size_t)NROWA*4);
  float*  RS2   = (float*)take((size_t)NROWA*4);
  float*  RMIN  = (float*)take((size_t)NROWA*4);
  float*  NEGL  = (float*)take((size_t)NROWA*4);
  float*  NEGR  = (float*)take((size_t)NROWA*4);
  float*  MM    = (float*)take((size_t)NROWA*4);
  float*  CCv   = (float*)take((size_t)NROWA*4);
  float*  ALv   = (float*)take((size_t)NROWA*4);
  float*  REXP  = (float*)take((size_t)NROWA*4);

  // ---- graph-phase region (dead after packE/packA) — overlapped by NEG16 ----
  size_t offG = off;
  float*  OUT  = (float*)take((size_t)N_NODE*OUTD*4);      // 92.16 MB
  __bf16* TRI  = (__bf16*)take((size_t)N_TRI*DIM*2);       // 51.2 MB
  float*  ATT4 = (float*)take((size_t)4*N_TRI*4);          // 3.2 MB
  int* RP_E  = (int*)take((size_t)(N_NODE+1)*4);
  int* RP_R  = (int*)take((size_t)(N_NODE+1)*4);
  int* RP_A  = (int*)take((size_t)(N_NODE+1)*4);
  int* IDX_E = (int*)take((size_t)N_TRI*4);
  int* IDX_R = (int*)take((size_t)N_TRI*4);
  int* IDX_A = (int*)take((size_t)N_TRI*4);
  int* CNT6  = (int*)take((size_t)6*N_NODE*4);
  int* CNT_E = CNT6,            *CNT_R = CNT6 + N_NODE,   *CNT_A = CNT6 + 2*N_NODE;
  int* CUR_E = CNT6 + 3*N_NODE, *CUR_R = CNT6 + 4*N_NODE, *CUR_A = CNT6 + 5*N_NODE;

  // NEG16 overlaps the graph-phase region (dead at GEMM time)
  _Float16* NEG16 = (_Float16*)(base + offG);
  size_t needFast = offG + (size_t)NROWA*EPAD*2;   // ~299 MB total
  bool fast = (ws_size >= needFast);

  // ---- init ----
  k_fill<<<192,256,0,stream>>>((float*)CNT6, (long)6*N_NODE, 0.f);

  // ---- CSR builds ----
  k_hist<<<782,256,0,stream>>>(ent_adj, CNT_E);
  k_hist<<<782,256,0,stream>>>(rel_adj, CNT_R);
  k_hist<<<782,256,0,stream>>>(adj,     CNT_A);
  k_scan3<<<3,256,0,stream>>>(CNT_E, RP_E, CNT_R, RP_R, CNT_A, RP_A, N_NODE);
  k_place<<<782,256,0,stream>>>(ent_adj, ent_adj+N_TRI, RP_E, CUR_E, IDX_E, 1);
  k_place<<<782,256,0,stream>>>(rel_adj, rel_adj+N_TRI, RP_R, CUR_R, IDX_R, 1);
  k_place<<<782,256,0,stream>>>(adj,     (const int*)0, RP_A, CUR_A, IDX_A, 0);

  // ---- feature pipeline ----
  k_feat0<<<7500,256,0,stream>>>(RP_E, IDX_E, RP_R, IDX_R, ent_emb, rel_emb, OUT);
  k_trinorm<<<50000,256,0,stream>>>(r_index+N_TRI, r_val, rel_emb, TRI, attn_e, attn_r, ATT4);
  k_gat<<<7500,256,0,stream>>>(RP_A, IDX_A, adj+N_TRI, TRI,
                               ATT4 + 0*N_TRI, ATT4 + 2*N_TRI, OUT, 0, 128, 384, 512);
  k_gat<<<7500,256,0,stream>>>(RP_A, IDX_A, adj+N_TRI, TRI,
                               ATT4 + 1*N_TRI, ATT4 + 3*N_TRI, OUT, 128, 256, 512, 640);

  // ---- loss prep ----
  k_packE<<<7520,256,0,stream>>>(OUT, EP, ESQ);
  k_packA<<<512,256,0,stream>>>(pairs, EP, OUT, ESQ, AP, ASQ, POS);
  k_fill<<<16,256,0,stream>>>(RS1, (long)NROWA, 0.f);
  k_fill<<<16,256,0,stream>>>(RS2, (long)NROWA, 0.f);
  k_fill<<<16,256,0,stream>>>(RMIN,(long)NROWA, 1e30f);

  // ---- pass 1: GEMM + moments (+neg16 store on fast path) ----
  dim3 gg(NTILE_A, NTILE_E, 1);
  k_gemm<<<gg,256,0,stream>>>(AP, EP, ASQ, ESQ, POS, pairs,
                              RS1, RS2, RMIN, CCv, ALv, REXP,
                              fast ? NEG16 : (_Float16*)nullptr, 1);
  k_corr<<<1024,256,0,stream>>>(pairs, AP, EP, ASQ, ESQ, NEGL, NEGR);
  k_stats<<<16,256,0,stream>>>(RS1, RS2, RMIN, NEGL, NEGR, ASQ, POS, pairs,
                               MM, CCv, ALv, REXP);

  // ---- pass 2 ----
  if (fast){
    k_p2s<<<gg,256,0,stream>>>(NEG16, CCv, ALv, pairs, REXP);
  } else {
    k_gemm<<<gg,256,0,stream>>>(AP, EP, ASQ, ESQ, POS, pairs,
                                RS1, RS2, RMIN, CCv, ALv, REXP,
                                (_Float16*)nullptr, 2);
  }
  k_final<<<1,256,0,stream>>>(MM, REXP, (float*)d_out);
}